// Round 1
// baseline (299.625 us; speedup 1.0000x reference)
//
#include <hip/hip_runtime.h>

#define C_IN 7
#define D_MODEL 512
#define KERNELS 73
#define MM 5
#define BB 32
#define LL 4096
#define TCHUNK 256
#define NTAP 18

__global__ __launch_bounds__(512) void tokemb_kernel(
    const float* __restrict__ x, const float* __restrict__ conv_w,
    const float* __restrict__ conv_b, const float* __restrict__ leftout_w,
    const float* __restrict__ leftout_b, float* __restrict__ out)
{
  __shared__ float xs[(TCHUNK + NTAP) * C_IN];
  const int tid = threadIdx.x;
  const int b = blockIdx.y;
  const int T0 = blockIdx.x * TCHUNK;

  // Stage x[b, T0-16 .. T0+TCHUNK+1, :] (time-wrapped) into LDS, layout [t][c].
  const int nelem = (TCHUNK + NTAP) * C_IN;
  const float* xb = x + (size_t)b * LL * C_IN;
  for (int e = tid; e < nelem; e += 512) {
    int q = e / C_IN;
    int r = e - q * C_IN;
    int p = T0 - 16 + q;
    if (p < 0) p += LL;
    else if (p >= LL) p -= LL;
    xs[e] = xb[p * C_IN + r];
  }

  // Per-thread FIR taps: wf[n] = w[k][m][j], m=n/3, j=2-(n%3)  (n = 3m+2-j)
  const int d = tid;
  const bool left = (d == D_MODEL - 1);
  int cc, kk;
  if (left) { cc = C_IN - 1; kk = 0; }
  else { cc = d / KERNELS; kk = d - cc * KERNELS; }
  const float* wsrc = left ? leftout_w : (conv_w + kk * (MM + 1) * 3);
  float wf[NTAP];
  #pragma unroll
  for (int n = 0; n < NTAP; ++n) {
    int m = n / 3, j = 2 - (n % 3);
    wf[n] = wsrc[m * 3 + j];
  }
  const float bias = left ? leftout_b[0] : conv_b[kk];

  __syncthreads();

  // Sliding window: win[n] = x[b, (t+1-n) mod L, cc]; preload for t = T0.
  float win[NTAP];
  #pragma unroll
  for (int n = 0; n < NTAP; ++n) win[n] = xs[(17 - n) * C_IN + cc];

  float* outb = out + ((size_t)b * LL + T0) * D_MODEL + d;

  for (int tl = 0; tl < TCHUNK; ++tl) {
    const int t = T0 + tl;
    float acc = bias;
    if (t >= 16 && t != LL - 1) {
      #pragma unroll
      for (int n = 0; n < NTAP; ++n) acc += win[n] * wf[n];
    } else {
      // boundary: zero-padded delay embedding (u<15) / circular edge
      #pragma unroll
      for (int j = 0; j < 3; ++j) {
        int u = t - 1 + j;
        if (u < 0) u += LL;
        else if (u >= LL) u -= LL;
        if (u >= 15) {
          #pragma unroll
          for (int m = 0; m <= MM; ++m) {
            const int n = 3 * m + 2 - j;
            acc += win[n] * wf[n];
          }
        }
      }
    }
    outb[(size_t)tl * D_MODEL] = acc;
    // slide: win'[n] = win[n-1]; win'[0] = x[t+2]
    #pragma unroll
    for (int n = NTAP - 1; n >= 1; --n) win[n] = win[n - 1];
    win[0] = xs[(tl + NTAP) * C_IN + cc];
  }
}

extern "C" void kernel_launch(void* const* d_in, const int* in_sizes, int n_in,
                              void* d_out, int out_size, void* d_ws, size_t ws_size,
                              hipStream_t stream) {
  const float* x = (const float*)d_in[0];
  const float* conv_w = (const float*)d_in[1];
  const float* conv_b = (const float*)d_in[2];
  const float* leftout_w = (const float*)d_in[3];
  const float* leftout_b = (const float*)d_in[4];
  float* out = (float*)d_out;
  dim3 grid(LL / TCHUNK, BB);
  tokemb_kernel<<<grid, 512, 0, stream>>>(x, conv_w, conv_b, leftout_w, leftout_b, out);
}

// Round 2
// 280.717 us; speedup vs baseline: 1.0674x; 1.0674x over previous
//
#include <hip/hip_runtime.h>

#define C_IN 7
#define D_MODEL 512
#define KERNELS 73
#define MM 5
#define BBATCH 32
#define LL 4096
#define TCHUNK 72          // multiple of NTAP; ceil(4096/72)=57 t-blocks
#define NTAP 18
#define XS_LD (TCHUNK + NTAP)   // 90 floats per channel (16 halo before, 2 after)

__global__ __launch_bounds__(512) void tokemb_kernel(
    const float* __restrict__ x, const float* __restrict__ conv_w,
    const float* __restrict__ conv_b, const float* __restrict__ leftout_w,
    const float* __restrict__ leftout_b, float* __restrict__ out)
{
  __shared__ float xs[C_IN * XS_LD];
  const int tid = threadIdx.x;
  const int b = blockIdx.y;
  const int T0 = blockIdx.x * TCHUNK;

  // Stage x[b, T0-16 .. T0+TCHUNK+1, :] (wrapped) into LDS, channel-major.
  const float* xb = x + (size_t)b * LL * C_IN;
  for (int e = tid; e < C_IN * XS_LD; e += 512) {
    int c = e / XS_LD;
    int q = e - c * XS_LD;
    int p = T0 - 16 + q;
    if (p < 0) p += LL;
    else if (p >= LL) p -= LL;
    xs[e] = xb[p * C_IN + c];
  }

  // Per-thread FIR taps: wf[n] = w[k][m][j], m=n/3, j=2-(n%3)
  const int d = tid;
  const bool left = (d == D_MODEL - 1);
  int cc, kk;
  if (left) { cc = C_IN - 1; kk = 0; }
  else { cc = d / KERNELS; kk = d - cc * KERNELS; }
  const float* wsrc = left ? leftout_w : (conv_w + kk * (MM + 1) * 3);
  float wf[NTAP];
  #pragma unroll
  for (int n = 0; n < NTAP; ++n) {
    int m = n / 3, j = 2 - (n % 3);
    wf[n] = wsrc[m * 3 + j];
  }
  const float bias = left ? leftout_b[0] : conv_b[kk];

  __syncthreads();

  const float* xc = xs + cc * XS_LD;

  // Circular register window. Invariant before global sub-iter s = tl0+u:
  // phys p holds xs-index q with q ≡ p (mod 18), q ∈ [s, s+18).
  float win[NTAP];
  #pragma unroll
  for (int p = 0; p < NTAP; ++p) win[p] = xc[p];

  float* outb = out + ((size_t)b * LL + T0) * D_MODEL + d;

  for (int tl0 = 0; tl0 < TCHUNK; tl0 += NTAP) {
    const int tg = T0 + tl0;
    if (tg >= 16 && tg <= LL - 1 - NTAP) {
      // clean: all 18 t's fully interior -> pure FMA, zero moves
      #pragma unroll
      for (int u = 0; u < NTAP; ++u) {
        float acc = bias;
        #pragma unroll
        for (int n = 0; n < NTAP; ++n)
          acc += win[(u + 17 - n) % NTAP] * wf[n];
        outb[(size_t)(tl0 + u) * D_MODEL] = acc;
        win[u] = xc[tl0 + u + NTAP];   // xs index s+18 -> phys (s%18)==u
      }
    } else {
      // boundary: zero-padded delay embedding (uu<15) / circular edge / t>=LL
      #pragma unroll
      for (int u = 0; u < NTAP; ++u) {
        const int t = tg + u;
        float acc = bias;
        #pragma unroll
        for (int j = 0; j < 3; ++j) {
          int uu = t - 1 + j;
          if (uu < 0) uu += LL;
          else if (uu >= LL) uu -= LL;
          if (uu >= 15) {
            #pragma unroll
            for (int m = 0; m <= MM; ++m) {
              const int n = 3 * m + 2 - j;
              acc += win[(u + 17 - n) % NTAP] * wf[n];
            }
          }
        }
        if (t < LL) outb[(size_t)(tl0 + u) * D_MODEL] = acc;
        win[u] = xc[tl0 + u + NTAP];
      }
    }
  }
}

extern "C" void kernel_launch(void* const* d_in, const int* in_sizes, int n_in,
                              void* d_out, int out_size, void* d_ws, size_t ws_size,
                              hipStream_t stream) {
  const float* x = (const float*)d_in[0];
  const float* conv_w = (const float*)d_in[1];
  const float* conv_b = (const float*)d_in[2];
  const float* leftout_w = (const float*)d_in[3];
  const float* leftout_b = (const float*)d_in[4];
  float* out = (float*)d_out;
  dim3 grid((LL + TCHUNK - 1) / TCHUNK, BBATCH);
  tokemb_kernel<<<grid, 512, 0, stream>>>(x, conv_w, conv_b, leftout_w, leftout_b, out);
}